// Round 2
// baseline (156.128 us; speedup 1.0000x reference)
//
#include <hip/hip_runtime.h>
#include <hip/hip_bf16.h>
#include <math.h>

// Problem constants: logits (2048, 3, 32000) f32, targets (2048, 4) int
#define VOCAB   32000
#define BATCH   2048
#define SEQ     3
#define ROWS    (BATCH * SEQ)        // 6144 softmax rows
#define THREADS 320                  // 5 waves; 32000/4 = 8000 float4 = 320 * 25
#define CHUNK   5                    // loads in flight per wave (x2 with prefetch)
#define NCHUNK  5                    // 5 chunks * 5 loads = 25 float4/thread
#define NBINS   15

// Combine two online-softmax partials (max m, scaled sum s, argmax idx).
// Tie-break: smaller global index (first occurrence), matching jnp.argmax.
__device__ __forceinline__ void combine(float& m, float& s, int& idx,
                                        float m2, float s2, int idx2) {
    if (m2 > m)      { s = s * __expf(m - m2) + s2; m = m2; idx = idx2; }
    else if (m2 < m) { s = s + s2 * __expf(m2 - m); }
    else             { s += s2; idx = (idx2 < idx) ? idx2 : idx; }
}

// One block per row: online max / sum-of-exp / argmax in a single HBM pass.
// 5-deep load batches + next-chunk prefetch keep ~10 dwordx4 in flight/wave.
__global__ __launch_bounds__(THREADS) void row_softmax_stats(
        const float* __restrict__ logits,
        float* __restrict__ maxprob,   // [ROWS] = 1/sumexp = max softmax prob
        int*   __restrict__ amax)      // [ROWS] = argmax index
{
    const int row = blockIdx.x;
    const int t   = threadIdx.x;
    const float4* base = (const float4*)(logits + (size_t)row * VOCAB);

    float m = -INFINITY;
    float s0 = 0.f, s1 = 0.f, s2 = 0.f, s3 = 0.f;   // independent partial sums
    int   idx = 0;

    float4 cur[CHUNK], nxt[CHUNK];
    #pragma unroll
    for (int u = 0; u < CHUNK; ++u) cur[u] = base[t + THREADS * u];

    #pragma unroll
    for (int c = 0; c < NCHUNK; ++c) {
        if (c + 1 < NCHUNK) {
            #pragma unroll
            for (int u = 0; u < CHUNK; ++u)
                nxt[u] = base[t + THREADS * ((c + 1) * CHUNK + u)];
        }
        #pragma unroll
        for (int u = 0; u < CHUNK; ++u) {
            float4 v = cur[u];
            float lm = fmaxf(fmaxf(v.x, v.y), fmaxf(v.z, v.w));
            if (lm > m) {                         // strict >: first occurrence wins
                float sc = __expf(m - lm);        // m==-inf -> 0, sums are 0 anyway
                s0 *= sc; s1 *= sc; s2 *= sc; s3 *= sc;
                m = lm;
                const int f4 = t + THREADS * (c * CHUNK + u);
                idx = f4 * 4 + ((v.x == lm) ? 0 : (v.y == lm) ? 1 : (v.z == lm) ? 2 : 3);
            }
            s0 += __expf(v.x - m);
            s1 += __expf(v.y - m);
            s2 += __expf(v.z - m);
            s3 += __expf(v.w - m);
        }
        #pragma unroll
        for (int u = 0; u < CHUNK; ++u) cur[u] = nxt[u];
    }

    float s = (s0 + s1) + (s2 + s3);

    // wave (64-lane) shuffle reduce
    for (int off = 32; off > 0; off >>= 1) {
        float m2 = __shfl_down(m, off);
        float sx = __shfl_down(s, off);
        int   i2 = __shfl_down(idx, off);
        combine(m, s, idx, m2, sx, i2);
    }

    // 5 waves -> LDS -> thread 0
    __shared__ float sm[THREADS / 64], ss[THREADS / 64];
    __shared__ int   si[THREADS / 64];
    const int wave = t >> 6;
    if ((t & 63) == 0) { sm[wave] = m; ss[wave] = s; si[wave] = idx; }
    __syncthreads();
    if (t == 0) {
        for (int w = 1; w < THREADS / 64; ++w) combine(m, s, idx, sm[w], ss[w], si[w]);
        maxprob[row] = 1.0f / s;   // exp(xmax-xmax)=1 exactly -> max prob = 1/s
        amax[row]    = idx;
    }
}

// Single block, 1024 threads: confidences, accuracies, 15-bin ECE. O(B) work.
__global__ __launch_bounds__(1024) void ece_reduce(
        const float* __restrict__ maxprob,
        const int*   __restrict__ amax,
        const int*   __restrict__ targets,   // [B][4] int32
        float*       __restrict__ out)
{
    const int t = threadIdx.x;

    float c_cnt[NBINS], c_conf[NBINS], c_acc[NBINS];
    #pragma unroll
    for (int i = 0; i < NBINS; ++i) { c_cnt[i] = 0.f; c_conf[i] = 0.f; c_acc[i] = 0.f; }

    #pragma unroll
    for (int r = 0; r < BATCH / 1024; ++r) {
        const int b = t + r * 1024;
        float p0 = maxprob[b * 3 + 0];
        float p1 = maxprob[b * 3 + 1];
        float p2 = maxprob[b * 3 + 2];
        float conf = (p0 * p1) * p2;             // jnp.prod order

        float acc = 0.f;
        acc += (amax[b * 3 + 0] == targets[b * 4 + 1]) ? 1.f : 0.f;
        acc += (amax[b * 3 + 1] == targets[b * 4 + 2]) ? 1.f : 0.f;
        acc += (amax[b * 3 + 2] == targets[b * 4 + 3]) ? 1.f : 0.f;
        float row_acc = acc * (1.0f / 3.0f);     // jnp.mean over 3

        // static-index bin accumulate (runtime-indexed arrays would spill)
        #pragma unroll
        for (int i = 0; i < NBINS; ++i) {
            float lo = (float)i       * (1.0f / 15.0f);
            float up = (float)(i + 1) * (1.0f / 15.0f);
            bool in = (conf > lo) && (conf <= up);
            if (in) { c_cnt[i] += 1.f; c_conf[i] += conf; c_acc[i] += row_acc; }
        }
    }

    // wave reduce each accumulator
    #pragma unroll
    for (int i = 0; i < NBINS; ++i) {
        for (int off = 32; off > 0; off >>= 1) {
            c_cnt[i]  += __shfl_down(c_cnt[i],  off);
            c_conf[i] += __shfl_down(c_conf[i], off);
            c_acc[i]  += __shfl_down(c_acc[i],  off);
        }
    }

    __shared__ float s_cnt[NBINS], s_conf[NBINS], s_acc[NBINS];
    if (t < NBINS) { s_cnt[t] = 0.f; s_conf[t] = 0.f; s_acc[t] = 0.f; }
    __syncthreads();
    if ((t & 63) == 0) {
        #pragma unroll
        for (int i = 0; i < NBINS; ++i) {
            atomicAdd(&s_cnt[i],  c_cnt[i]);
            atomicAdd(&s_conf[i], c_conf[i]);
            atomicAdd(&s_acc[i],  c_acc[i]);
        }
    }
    __syncthreads();
    if (t == 0) {
        float ece = 0.f;
        #pragma unroll
        for (int i = 0; i < NBINS; ++i) {
            float cnt = s_cnt[i];
            if (cnt > 0.f) {
                float prop     = cnt / (float)BATCH;
                float safe_cnt = fmaxf(cnt, 1.0f);
                float avg_conf = s_conf[i] / safe_cnt;
                float avg_acc  = s_acc[i]  / safe_cnt;
                ece += fabsf(avg_conf - avg_acc) * prop;
            }
        }
        out[0] = ece;
    }
}

extern "C" void kernel_launch(void* const* d_in, const int* in_sizes, int n_in,
                              void* d_out, int out_size, void* d_ws, size_t ws_size,
                              hipStream_t stream) {
    const float* logits  = (const float*)d_in[0];
    const int*   targets = (const int*)d_in[1];   // harness: integer -> const int*
    float*       out     = (float*)d_out;

    float* maxprob = (float*)d_ws;                                   // 6144 floats
    int*   amax    = (int*)((char*)d_ws + ROWS * sizeof(float));     // 6144 ints

    row_softmax_stats<<<ROWS, THREADS, 0, stream>>>(logits, maxprob, amax);
    ece_reduce<<<1, 1024, 0, stream>>>(maxprob, amax, targets, out);
}

// Round 4
// 138.278 us; speedup vs baseline: 1.1291x; 1.1291x over previous
//
#include <hip/hip_runtime.h>
#include <hip/hip_bf16.h>
#include <math.h>

// Problem constants: logits (2048, 3, 32000) f32, targets (2048, 4) int
#define VOCAB     32000
#define BATCH     2048
#define SEQ       3
#define ROWS      (BATCH * SEQ)      // 6144 softmax rows
#define WPB       4                  // waves per block, one row per wave
#define BLOCKSZ   (WPB * 64)
#define NF4       (VOCAB / 4 / 64)   // 125 float4 per lane
#define NBINS     15

typedef float f32x4 __attribute__((ext_vector_type(4)));  // clang vector: OK for nontemporal builtin

// Combine two online-softmax partials (max m, scaled sum s, argmax idx).
// Tie-break: smaller global index (first occurrence), matching jnp.argmax.
__device__ __forceinline__ void combine(float& m, float& s, int& idx,
                                        float m2, float s2, int idx2) {
    if (m2 > m)      { s = s * __expf(m - m2) + s2; m = m2; idx = idx2; }
    else if (m2 < m) { s = s + s2 * __expf(m2 - m); }
    else             { s += s2; idx = (idx2 < idx) ? idx2 : idx; }
}

// One WAVE per row: online max / sum-of-exp / argmax in a single HBM pass.
// No LDS, no __syncthreads; all 6144 waves resident simultaneously (24/CU).
__global__ __launch_bounds__(BLOCKSZ) void row_softmax_stats(
        const float* __restrict__ logits,
        float* __restrict__ maxprob,   // [ROWS] = 1/sumexp = max softmax prob
        int*   __restrict__ amax)      // [ROWS] = argmax index
{
    const int wave = threadIdx.x >> 6;
    const int lane = threadIdx.x & 63;
    const int row  = blockIdx.x * WPB + wave;
    const f32x4* base = (const f32x4*)(logits + (size_t)row * VOCAB);

    float m = -INFINITY;
    float s0 = 0.f, s1 = 0.f, s2 = 0.f, s3 = 0.f;   // independent partial sums
    int   idx = 0;

    #pragma unroll 5
    for (int i = 0; i < NF4; ++i) {
        const int f4 = lane + 64 * i;                 // wave-contiguous 1KB segments
        f32x4 v = __builtin_nontemporal_load(base + f4);   // read-once stream (nt)
        float lm = fmaxf(fmaxf(v.x, v.y), fmaxf(v.z, v.w));
        if (lm > m) {                                 // strict >: first occurrence
            float sc = __expf(m - lm);                // m==-inf -> 0, sums are 0
            s0 *= sc; s1 *= sc; s2 *= sc; s3 *= sc;
            m = lm;
            idx = f4 * 4 + ((v.x == lm) ? 0 : (v.y == lm) ? 1 : (v.z == lm) ? 2 : 3);
        }
        s0 += __expf(v.x - m);
        s1 += __expf(v.y - m);
        s2 += __expf(v.z - m);
        s3 += __expf(v.w - m);
    }

    float s = (s0 + s1) + (s2 + s3);

    // wave (64-lane) shuffle reduce — the only cross-lane step
    for (int off = 32; off > 0; off >>= 1) {
        float m2 = __shfl_down(m, off);
        float sx = __shfl_down(s, off);
        int   i2 = __shfl_down(idx, off);
        combine(m, s, idx, m2, sx, i2);
    }

    if (lane == 0) {
        maxprob[row] = 1.0f / s;   // exp(xmax-xmax)=1 exactly -> max prob = 1/s
        amax[row]    = idx;
    }
}

// Single block, 1024 threads: confidences, accuracies, 15-bin ECE. O(B) work.
__global__ __launch_bounds__(1024) void ece_reduce(
        const float* __restrict__ maxprob,
        const int*   __restrict__ amax,
        const int*   __restrict__ targets,   // [B][4] int32
        float*       __restrict__ out)
{
    const int t = threadIdx.x;

    float c_cnt[NBINS], c_conf[NBINS], c_acc[NBINS];
    #pragma unroll
    for (int i = 0; i < NBINS; ++i) { c_cnt[i] = 0.f; c_conf[i] = 0.f; c_acc[i] = 0.f; }

    #pragma unroll
    for (int r = 0; r < BATCH / 1024; ++r) {
        const int b = t + r * 1024;
        float p0 = maxprob[b * 3 + 0];
        float p1 = maxprob[b * 3 + 1];
        float p2 = maxprob[b * 3 + 2];
        float conf = (p0 * p1) * p2;             // jnp.prod order

        float acc = 0.f;
        acc += (amax[b * 3 + 0] == targets[b * 4 + 1]) ? 1.f : 0.f;
        acc += (amax[b * 3 + 1] == targets[b * 4 + 2]) ? 1.f : 0.f;
        acc += (amax[b * 3 + 2] == targets[b * 4 + 3]) ? 1.f : 0.f;
        float row_acc = acc * (1.0f / 3.0f);     // jnp.mean over 3

        // static-index bin accumulate (runtime-indexed arrays would spill)
        #pragma unroll
        for (int i = 0; i < NBINS; ++i) {
            float lo = (float)i       * (1.0f / 15.0f);
            float up = (float)(i + 1) * (1.0f / 15.0f);
            bool in = (conf > lo) && (conf <= up);
            if (in) { c_cnt[i] += 1.f; c_conf[i] += conf; c_acc[i] += row_acc; }
        }
    }

    // wave reduce each accumulator
    #pragma unroll
    for (int i = 0; i < NBINS; ++i) {
        for (int off = 32; off > 0; off >>= 1) {
            c_cnt[i]  += __shfl_down(c_cnt[i],  off);
            c_conf[i] += __shfl_down(c_conf[i], off);
            c_acc[i]  += __shfl_down(c_acc[i],  off);
        }
    }

    __shared__ float s_cnt[NBINS], s_conf[NBINS], s_acc[NBINS];
    if (t < NBINS) { s_cnt[t] = 0.f; s_conf[t] = 0.f; s_acc[t] = 0.f; }
    __syncthreads();
    if ((t & 63) == 0) {
        #pragma unroll
        for (int i = 0; i < NBINS; ++i) {
            atomicAdd(&s_cnt[i],  c_cnt[i]);
            atomicAdd(&s_conf[i], c_conf[i]);
            atomicAdd(&s_acc[i],  c_acc[i]);
        }
    }
    __syncthreads();
    if (t == 0) {
        float ece = 0.f;
        #pragma unroll
        for (int i = 0; i < NBINS; ++i) {
            float cnt = s_cnt[i];
            if (cnt > 0.f) {
                float prop     = cnt / (float)BATCH;
                float safe_cnt = fmaxf(cnt, 1.0f);
                float avg_conf = s_conf[i] / safe_cnt;
                float avg_acc  = s_acc[i]  / safe_cnt;
                ece += fabsf(avg_conf - avg_acc) * prop;
            }
        }
        out[0] = ece;
    }
}

extern "C" void kernel_launch(void* const* d_in, const int* in_sizes, int n_in,
                              void* d_out, int out_size, void* d_ws, size_t ws_size,
                              hipStream_t stream) {
    const float* logits  = (const float*)d_in[0];
    const int*   targets = (const int*)d_in[1];   // harness: integer -> const int*
    float*       out     = (float*)d_out;

    float* maxprob = (float*)d_ws;                                   // 6144 floats
    int*   amax    = (int*)((char*)d_ws + ROWS * sizeof(float));     // 6144 ints

    row_softmax_stats<<<ROWS / WPB, BLOCKSZ, 0, stream>>>(logits, maxprob, amax);
    ece_reduce<<<1, 1024, 0, stream>>>(maxprob, amax, targets, out);
}

// Round 5
// 127.153 us; speedup vs baseline: 1.2279x; 1.0875x over previous
//
#include <hip/hip_runtime.h>
#include <hip/hip_bf16.h>
#include <math.h>

// Problem constants: logits (2048, 3, 32000) f32, targets (2048, 4) int
#define VOCAB     32000
#define BATCH     2048
#define SEQ       3
#define ROWS      (BATCH * SEQ)      // 6144 softmax rows
#define BLOCKSZ   (SEQ * 64)         // one block = one batch = 3 waves, one row each
#define NF4       (VOCAB / 4 / 64)   // 125 float4 per lane
#define NBINS     15
#define NREP      8                  // replicated bin sets to spread atomic contention
#define REPSTRIDE 64                 // floats per replica (256 B, cacheline-separated)

typedef float f32x4 __attribute__((ext_vector_type(4)));  // clang vector for nontemporal builtin

// Combine two online-softmax partials (max m, scaled sum s, argmax idx).
// Tie-break: smaller global index (first occurrence), matching jnp.argmax.
__device__ __forceinline__ void combine(float& m, float& s, int& idx,
                                        float m2, float s2, int idx2) {
    if (m2 > m)      { s = s * __expf(m - m2) + s2; m = m2; idx = idx2; }
    else if (m2 < m) { s = s + s2 * __expf(m2 - m); }
    else             { s += s2; idx = (idx2 < idx) ? idx2 : idx; }
}

// One block per BATCH: 3 waves, each owns one softmax row (single HBM pass),
// then the block bins its confidence/accuracy into replicated global bins.
// Replica layout: bins[rep*64 + {0..14:count, 16..30:conf, 32..46:acc}]
__global__ __launch_bounds__(BLOCKSZ) void ece_fused(
        const float* __restrict__ logits,
        const int*   __restrict__ targets,   // [B][4] int32
        float*       __restrict__ bins)      // [NREP * REPSTRIDE], pre-zeroed
{
    const int wave = threadIdx.x >> 6;
    const int lane = threadIdx.x & 63;
    const int b    = blockIdx.x;
    const int row  = b * SEQ + wave;
    const f32x4* base = (const f32x4*)(logits + (size_t)row * VOCAB);

    float m = -INFINITY;
    float s0 = 0.f, s1 = 0.f, s2 = 0.f, s3 = 0.f;   // independent partial sums
    int   idx = 0;

    #pragma unroll 5
    for (int i = 0; i < NF4; ++i) {
        const int f4 = lane + 64 * i;                 // wave-contiguous 1KB segments
        f32x4 v = __builtin_nontemporal_load(base + f4);   // read-once stream (nt)
        float lm = fmaxf(fmaxf(v.x, v.y), fmaxf(v.z, v.w));
        if (lm > m) {                                 // strict >: first occurrence
            float sc = __expf(m - lm);                // m==-inf -> 0, sums are 0
            s0 *= sc; s1 *= sc; s2 *= sc; s3 *= sc;
            m = lm;
            idx = f4 * 4 + ((v.x == lm) ? 0 : (v.y == lm) ? 1 : (v.z == lm) ? 2 : 3);
        }
        s0 += __expf(v.x - m);
        s1 += __expf(v.y - m);
        s2 += __expf(v.z - m);
        s3 += __expf(v.w - m);
    }

    float s = (s0 + s1) + (s2 + s3);

    // wave (64-lane) shuffle reduce — the only cross-lane step
    for (int off = 32; off > 0; off >>= 1) {
        float m2 = __shfl_down(m, off);
        float sx = __shfl_down(s, off);
        int   i2 = __shfl_down(idx, off);
        combine(m, s, idx, m2, sx, i2);
    }

    __shared__ float p[SEQ];
    __shared__ int   ix[SEQ];
    if (lane == 0) { p[wave] = 1.0f / s; ix[wave] = idx; }  // max prob = 1/sumexp
    __syncthreads();

    if (threadIdx.x == 0) {
        float conf = (p[0] * p[1]) * p[2];               // jnp.prod order
        float acc = 0.f;
        acc += (ix[0] == targets[b * 4 + 1]) ? 1.f : 0.f;
        acc += (ix[1] == targets[b * 4 + 2]) ? 1.f : 0.f;
        acc += (ix[2] == targets[b * 4 + 3]) ? 1.f : 0.f;
        float row_acc = acc * (1.0f / 3.0f);             // jnp.mean over 3

        // bin i iff conf > i/15 && conf <= (i+1)/15  ->  bin = #{k in 1..14 : conf > k/15}
        int bin = 0;
        #pragma unroll
        for (int k = 1; k < NBINS; ++k)
            bin += (conf > (float)k * (1.0f / 15.0f)) ? 1 : 0;

        float* rep = bins + (b & (NREP - 1)) * REPSTRIDE;
        atomicAdd(rep + bin,          1.0f);
        atomicAdd(rep + 16 + bin,     conf);
        atomicAdd(rep + 32 + bin,     row_acc);
    }
}

// One wave: fold 8 replicas -> 15 bins -> ECE scalar. Cross-dispatch visibility
// is guaranteed by the kernel-boundary cache flush/invalidate.
__global__ __launch_bounds__(64) void ece_final(
        const float* __restrict__ bins,
        float*       __restrict__ out)
{
    const int t = threadIdx.x;
    float per = 0.f;
    if (t < NBINS) {
        float cnt = 0.f, cf = 0.f, ac = 0.f;
        #pragma unroll
        for (int r = 0; r < NREP; ++r) {
            cnt += bins[r * REPSTRIDE + t];
            cf  += bins[r * REPSTRIDE + 16 + t];
            ac  += bins[r * REPSTRIDE + 32 + t];
        }
        if (cnt > 0.f) {
            float prop = cnt / (float)BATCH;
            float safe = fmaxf(cnt, 1.0f);
            per = fabsf(cf / safe - ac / safe) * prop;
        }
    }
    for (int off = 32; off > 0; off >>= 1) per += __shfl_down(per, off);
    if (t == 0) out[0] = per;
}

extern "C" void kernel_launch(void* const* d_in, const int* in_sizes, int n_in,
                              void* d_out, int out_size, void* d_ws, size_t ws_size,
                              hipStream_t stream) {
    const float* logits  = (const float*)d_in[0];
    const int*   targets = (const int*)d_in[1];   // harness: integer -> const int*
    float*       out     = (float*)d_out;
    float*       bins    = (float*)d_ws;          // NREP*REPSTRIDE floats = 2 KB

    hipMemsetAsync(bins, 0, NREP * REPSTRIDE * sizeof(float), stream);
    ece_fused<<<BATCH, BLOCKSZ, 0, stream>>>(logits, targets, bins);
    ece_final<<<1, 64, 0, stream>>>(bins, out);
}